// Round 1
// baseline (109.808 us; speedup 1.0000x reference)
//
#include <hip/hip_runtime.h>
#include <math.h>

#define NIMG 64
#define HW   1024
#define NCH  85
#define NCLS 80
#define CONF_TH 0.25f
#define NMS_TH  0.35f

// ---------------------------------------------------------------------------
// Kernel 1: decode. One thread per (image, pixel). Fully coalesced channel
// reads (channel-major layout: lane i -> consecutive hw index).
// ---------------------------------------------------------------------------
__global__ __launch_bounds__(256) void decode_kernel(const float* __restrict__ preds,
                                                     float* __restrict__ out) {
  int g = blockIdx.x * 256 + threadIdx.x;            // 0..65535 = n*1024 + t
  int t = g & (HW - 1);
  const float* base = preds + (size_t)(g >> 10) * (NCH * HW) + t;

  float pobj = base[0];
  float tx = base[1 * HW], ty = base[2 * HW];
  float tw = base[3 * HW], th = base[4 * HW];

  // argmax over 80 classes (first occurrence on ties, matching jnp.argmax)
  float best = base[5 * HW];
  int bc = 0;
  for (int c = 1; c < NCLS; ++c) {
    float v = base[(5 + c) * HW];
    if (v > best) { best = v; bc = c; }
  }
  float score = pobj * best;   // bit-exact vs reference (pure f32 mul/max chain)

  float gx = (float)(t & 31);
  float gy = (float)(t >> 5);
  // transcendentals in double, rounded to f32 (<=0.5ulp) to track the numpy ref
  float bcx = ((float)tanh((double)tx) + gx) * 0.03125f;  // /32 exact pow2
  float bcy = ((float)tanh((double)ty) + gy) * 0.03125f;
  float bw = (float)(1.0 / (1.0 + exp(-(double)tw)));
  float bh = (float)(1.0 / (1.0 + exp(-(double)th)));

  float x1 = bcx - 0.5f * bw, y1 = bcy - 0.5f * bh;
  float x2 = bcx + 0.5f * bw, y2 = bcy + 0.5f * bh;

  float* ob = out + (size_t)g * 6;
  ob[0] = x1; ob[1] = y1; ob[2] = x2; ob[3] = y2;
  ob[4] = score; ob[5] = (float)bc;
}

// ---------------------------------------------------------------------------
// Kernel 2: class-aware NMS. One block per image. Suppression only occurs
// within a class, and JAX's stable descending argsort restricted to a class
// equals ordering by (score desc, original idx asc). So: bucket valid boxes
// by class, sort each bucket, greedy-NMS each bucket serially (m ~ 6 avg).
// ---------------------------------------------------------------------------
__global__ __launch_bounds__(1024) void nms_kernel(const float* __restrict__ bboxes,
                                                   float* __restrict__ keepOut) {
  int n = blockIdx.x;
  int t = threadIdx.x;

  __shared__ float sx1[HW], sy1[HW], sx2[HW], sy2[HW], sarea[HW], sscore[HW];
  __shared__ int bucket[HW];
  __shared__ unsigned char skept[HW];
  __shared__ int cnt[NCLS], offs[NCLS];

  size_t gb = (size_t)n * HW + t;
  const float* bb = bboxes + gb * 6;
  float score = bb[4];
  int cls = (int)bb[5];

  if (t < NCLS) cnt[t] = 0;
  keepOut[gb] = 0.0f;          // default: not kept (covers invalid + suppressed)
  __syncthreads();

  bool valid = score > CONF_TH;
  if (valid) atomicAdd(&cnt[cls], 1);
  __syncthreads();

  if (t == 0) {
    int s = 0;
    for (int c = 0; c < NCLS; ++c) { offs[c] = s; s += cnt[c]; }
  }
  __syncthreads();

  if (valid) {
    float x1 = bb[0], y1 = bb[1], x2 = bb[2], y2 = bb[3];
    sx1[t] = x1; sy1[t] = y1; sx2[t] = x2; sy2[t] = y2;
    sarea[t] = (x2 - x1) * (y2 - y1);
    sscore[t] = score;
    int p = atomicAdd(&offs[cls], 1);
    bucket[p] = t;
  }
  __syncthreads();

  if (t < NCLS) {
    int m = cnt[t];
    int s0 = offs[t] - m;      // offs was advanced by the scatter

    // insertion sort bucket[s0..s0+m) by (score desc, idx asc) -- exact
    // reproduction of stable descending argsort restricted to this class
    for (int a = 1; a < m; ++a) {
      int key = bucket[s0 + a];
      float ks = sscore[key];
      int b = a - 1;
      while (b >= 0) {
        int ib = bucket[s0 + b];
        float sb = sscore[ib];
        bool before = (ks > sb) || (ks == sb && key < ib);
        if (before) { bucket[s0 + b + 1] = ib; --b; } else break;
      }
      bucket[s0 + b + 1] = key;
    }

    // greedy NMS over this class's boxes
    for (int a = 0; a < m; ++a) {
      int ia = bucket[s0 + a];
      float ax1 = sx1[ia], ay1 = sy1[ia], ax2 = sx2[ia], ay2 = sy2[ia];
      float aar = sarea[ia];
      bool kept = true;
      for (int b = 0; b < a; ++b) {
        if (!skept[s0 + b]) continue;
        int jb = bucket[s0 + b];
        float iw = fminf(ax2, sx2[jb]) - fmaxf(ax1, sx1[jb]);
        float ih = fminf(ay2, sy2[jb]) - fmaxf(ay1, sy1[jb]);
        iw = fmaxf(iw, 0.0f);
        ih = fmaxf(ih, 0.0f);
        float inter = iw * ih;
        float iou = inter / (aar + sarea[jb] - inter + 1e-9f);
        if (iou > NMS_TH) { kept = false; break; }
      }
      skept[s0 + a] = (unsigned char)kept;
      if (kept) keepOut[(size_t)n * HW + ia] = 1.0f;
    }
  }
}

extern "C" void kernel_launch(void* const* d_in, const int* in_sizes, int n_in,
                              void* d_out, int out_size, void* d_ws, size_t ws_size,
                              hipStream_t stream) {
  const float* preds = (const float*)d_in[0];
  float* out = (float*)d_out;
  float* keepOut = out + (size_t)NIMG * HW * 6;

  decode_kernel<<<(NIMG * HW) / 256, 256, 0, stream>>>(preds, out);
  nms_kernel<<<NIMG, HW, 0, stream>>>(out, keepOut);
}

// Round 2
// 106.697 us; speedup vs baseline: 1.0292x; 1.0292x over previous
//
#include <hip/hip_runtime.h>
#include <math.h>

#define NIMG 64
#define HW   1024
#define NCH  85
#define NCLS 80
#define CONF_TH 0.25f
#define NMS_TH  0.35f

__device__ __forceinline__ float fast_tanh(float x) {
  // tanh(x) = 1 - 2/(e^{2x}+1); saturates correctly at +-inf via __expf/v_rcp
  float e = __expf(2.0f * x);
  return 1.0f - 2.0f * __builtin_amdgcn_rcpf(e + 1.0f);
}
__device__ __forceinline__ float fast_sigmoid(float x) {
  return __builtin_amdgcn_rcpf(1.0f + __expf(-x));
}

// ---------------------------------------------------------------------------
// Kernel 1: decode. One thread per (image, pixel); coalesced channel reads.
// All f32 math (threshold 1.58 gives huge slack; score path is bit-exact).
// ---------------------------------------------------------------------------
__global__ __launch_bounds__(256) void decode_kernel(const float* __restrict__ preds,
                                                     float* __restrict__ out) {
  int g = blockIdx.x * 256 + threadIdx.x;            // n*1024 + t
  int t = g & (HW - 1);
  const float* base = preds + (size_t)(g >> 10) * (NCH * HW) + t;

  float pobj = base[0];
  float tx = base[1 * HW], ty = base[2 * HW];
  float tw = base[3 * HW], th = base[4 * HW];

  // argmax over 80 classes, 4 parallel chains, exact first-occurrence ties
  float b0 = base[5 * HW], b1 = base[6 * HW], b2 = base[7 * HW], b3 = base[8 * HW];
  int i0 = 0, i1 = 1, i2 = 2, i3 = 3;
#pragma unroll
  for (int c = 4; c < NCLS; c += 4) {
    float v0 = base[(5 + c) * HW];
    float v1 = base[(6 + c) * HW];
    float v2 = base[(7 + c) * HW];
    float v3 = base[(8 + c) * HW];
    if (v0 > b0) { b0 = v0; i0 = c; }
    if (v1 > b1) { b1 = v1; i1 = c + 1; }
    if (v2 > b2) { b2 = v2; i2 = c + 2; }
    if (v3 > b3) { b3 = v3; i3 = c + 3; }
  }
  float best = b0; int bc = i0;
  if (b1 > best || (b1 == best && i1 < bc)) { best = b1; bc = i1; }
  if (b2 > best || (b2 == best && i2 < bc)) { best = b2; bc = i2; }
  if (b3 > best || (b3 == best && i3 < bc)) { best = b3; bc = i3; }

  float score = pobj * best;   // bit-exact vs reference

  float gx = (float)(t & 31);
  float gy = (float)(t >> 5);
  float bcx = (fast_tanh(tx) + gx) * 0.03125f;   // /32 exact pow2 scale
  float bcy = (fast_tanh(ty) + gy) * 0.03125f;
  float bw = fast_sigmoid(tw);
  float bh = fast_sigmoid(th);

  float x1 = bcx - 0.5f * bw, y1 = bcy - 0.5f * bh;
  float x2 = bcx + 0.5f * bw, y2 = bcy + 0.5f * bh;

  float2* ob = (float2*)(out + (size_t)g * 6);   // 24B stride -> 8B aligned
  ob[0] = make_float2(x1, y1);
  ob[1] = make_float2(x2, y2);
  ob[2] = make_float2(score, (float)bc);
}

// ---------------------------------------------------------------------------
// Kernel 2: class-aware NMS, one block (256 thr) per image, 4 px/thread.
// Class-bucketed exact greedy NMS (suppression is same-class only; stable
// descending argsort within a class == order by (score desc, idx asc)).
// ---------------------------------------------------------------------------
__global__ __launch_bounds__(256) void nms_kernel(const float* __restrict__ bboxes,
                                                  float* __restrict__ keepOut) {
  int n = blockIdx.x;
  int t = threadIdx.x;

  __shared__ float sx1[HW], sy1[HW], sx2[HW], sy2[HW], sarea[HW], sscore[HW];
  __shared__ int scls[HW];
  __shared__ int bucket[HW];
  __shared__ unsigned char skept[HW];
  __shared__ int cnt[NCLS], offs[NCLS];

  if (t < NCLS) cnt[t] = 0;
  __syncthreads();

#pragma unroll
  for (int k = 0; k < 4; ++k) {
    int px = t + 256 * k;
    size_t gb = (size_t)n * HW + px;
    const float2* bb = (const float2*)(bboxes + gb * 6);
    float2 p0 = bb[0], p1 = bb[1], p2 = bb[2];
    keepOut[gb] = 0.0f;
    sx1[px] = p0.x; sy1[px] = p0.y; sx2[px] = p1.x; sy2[px] = p1.y;
    sarea[px] = (p1.x - p0.x) * (p1.y - p0.y);
    sscore[px] = p2.x;
    int cls = (int)p2.y;
    scls[px] = cls;
    if (p2.x > CONF_TH) atomicAdd(&cnt[cls], 1);
  }
  __syncthreads();

  if (t == 0) {
    int s = 0;
    for (int c = 0; c < NCLS; ++c) { offs[c] = s; s += cnt[c]; }
  }
  __syncthreads();

#pragma unroll
  for (int k = 0; k < 4; ++k) {
    int px = t + 256 * k;
    if (sscore[px] > CONF_TH) {
      int p = atomicAdd(&offs[scls[px]], 1);
      bucket[p] = px;
    }
  }
  __syncthreads();

  if (t < NCLS) {
    int m = cnt[t];
    int s0 = offs[t] - m;   // offs was advanced by the scatter

    // insertion sort by (score desc, idx asc) — exact stable-argsort semantics
    for (int a = 1; a < m; ++a) {
      int key = bucket[s0 + a];
      float ks = sscore[key];
      int b = a - 1;
      while (b >= 0) {
        int ib = bucket[s0 + b];
        float sb = sscore[ib];
        bool before = (ks > sb) || (ks == sb && key < ib);
        if (before) { bucket[s0 + b + 1] = ib; --b; } else break;
      }
      bucket[s0 + b + 1] = key;
    }

    // greedy NMS within the class
    for (int a = 0; a < m; ++a) {
      int ia = bucket[s0 + a];
      float ax1 = sx1[ia], ay1 = sy1[ia], ax2 = sx2[ia], ay2 = sy2[ia];
      float aar = sarea[ia];
      bool kept = true;
      for (int b = 0; b < a; ++b) {
        if (!skept[s0 + b]) continue;
        int jb = bucket[s0 + b];
        float iw = fminf(ax2, sx2[jb]) - fmaxf(ax1, sx1[jb]);
        float ih = fminf(ay2, sy2[jb]) - fmaxf(ay1, sy1[jb]);
        iw = fmaxf(iw, 0.0f);
        ih = fmaxf(ih, 0.0f);
        float inter = iw * ih;
        float iou = inter / (aar + sarea[jb] - inter + 1e-9f);
        if (iou > NMS_TH) { kept = false; break; }
      }
      skept[s0 + a] = (unsigned char)kept;
      if (kept) keepOut[(size_t)n * HW + ia] = 1.0f;
    }
  }
}

extern "C" void kernel_launch(void* const* d_in, const int* in_sizes, int n_in,
                              void* d_out, int out_size, void* d_ws, size_t ws_size,
                              hipStream_t stream) {
  const float* preds = (const float*)d_in[0];
  float* out = (float*)d_out;
  float* keepOut = out + (size_t)NIMG * HW * 6;

  decode_kernel<<<(NIMG * HW) / 256, 256, 0, stream>>>(preds, out);
  nms_kernel<<<NIMG, 256, 0, stream>>>(out, keepOut);
}

// Round 3
// 82.957 us; speedup vs baseline: 1.3237x; 1.2862x over previous
//
#include <hip/hip_runtime.h>
#include <math.h>

#define NIMG 64
#define HW   1024
#define NCH  85
#define NCLS 80
#define CONF_TH 0.25f
#define NMS_TH  0.35f

__device__ __forceinline__ float fast_tanh(float x) {
  float e = __expf(2.0f * x);
  return 1.0f - 2.0f * __builtin_amdgcn_rcpf(e + 1.0f);
}
__device__ __forceinline__ float fast_sigmoid(float x) {
  return __builtin_amdgcn_rcpf(1.0f + __expf(-x));
}

// ---------------------------------------------------------------------------
// Kernel 1: decode. One thread per (image, pixel); coalesced channel reads.
// ---------------------------------------------------------------------------
__global__ __launch_bounds__(256) void decode_kernel(const float* __restrict__ preds,
                                                     float* __restrict__ out) {
  int g = blockIdx.x * 256 + threadIdx.x;            // n*1024 + t
  int t = g & (HW - 1);
  const float* base = preds + (size_t)(g >> 10) * (NCH * HW) + t;

  float pobj = base[0];
  float tx = base[1 * HW], ty = base[2 * HW];
  float tw = base[3 * HW], th = base[4 * HW];

  // argmax over 80 classes, 4 chains, exact first-occurrence tie semantics
  float b0 = base[5 * HW], b1 = base[6 * HW], b2 = base[7 * HW], b3 = base[8 * HW];
  int i0 = 0, i1 = 1, i2 = 2, i3 = 3;
#pragma unroll
  for (int c = 4; c < NCLS; c += 4) {
    float v0 = base[(5 + c) * HW];
    float v1 = base[(6 + c) * HW];
    float v2 = base[(7 + c) * HW];
    float v3 = base[(8 + c) * HW];
    if (v0 > b0) { b0 = v0; i0 = c; }
    if (v1 > b1) { b1 = v1; i1 = c + 1; }
    if (v2 > b2) { b2 = v2; i2 = c + 2; }
    if (v3 > b3) { b3 = v3; i3 = c + 3; }
  }
  float best = b0; int bc = i0;
  if (b1 > best || (b1 == best && i1 < bc)) { best = b1; bc = i1; }
  if (b2 > best || (b2 == best && i2 < bc)) { best = b2; bc = i2; }
  if (b3 > best || (b3 == best && i3 < bc)) { best = b3; bc = i3; }

  float score = pobj * best;   // bit-exact vs reference

  float gx = (float)(t & 31);
  float gy = (float)(t >> 5);
  float bcx = (fast_tanh(tx) + gx) * 0.03125f;
  float bcy = (fast_tanh(ty) + gy) * 0.03125f;
  float bw = fast_sigmoid(tw);
  float bh = fast_sigmoid(th);

  float x1 = bcx - 0.5f * bw, y1 = bcy - 0.5f * bh;
  float x2 = bcx + 0.5f * bw, y2 = bcy + 0.5f * bh;

  float2* ob = (float2*)(out + (size_t)g * 6);
  ob[0] = make_float2(x1, y1);
  ob[1] = make_float2(x2, y2);
  ob[2] = make_float2(score, (float)bc);
}

// ---------------------------------------------------------------------------
// Kernel 2: class-aware NMS, one block (256 thr) per image, 4 px/thread.
// Parallel rank + parallel suppression-bitmask; only the O(m) greedy scan
// (register bit-ops) is serial per class.
// ---------------------------------------------------------------------------
__global__ __launch_bounds__(256) void nms_kernel(const float* __restrict__ bboxes,
                                                  float* __restrict__ keepOut) {
  int n = blockIdx.x;
  int t = threadIdx.x;

  __shared__ float sx1[HW], sy1[HW], sx2[HW], sy2[HW], sarea[HW], sscore[HW];
  __shared__ int scls[HW];
  __shared__ int bucket[HW];                 // unordered class members; later: fallback kept-flags
  __shared__ int sorted[HW];                 // class members in (score desc, idx asc) order
  __shared__ int srank[HW];                  // rank of pixel within its class
  __shared__ unsigned long long supp[HW];    // suppression bits vs lower ranks
  __shared__ int cnt[NCLS], offs[NCLS], start[NCLS];

  if (t < NCLS) cnt[t] = 0;
  __syncthreads();

  // ---- phase 1: load boxes to LDS, count valid per class ----
#pragma unroll
  for (int k = 0; k < 4; ++k) {
    int px = t + 256 * k;
    size_t gb = (size_t)n * HW + px;
    const float2* bb = (const float2*)(bboxes + gb * 6);
    float2 p0 = bb[0], p1 = bb[1], p2 = bb[2];
    keepOut[gb] = 0.0f;
    sx1[px] = p0.x; sy1[px] = p0.y; sx2[px] = p1.x; sy2[px] = p1.y;
    sarea[px] = (p1.x - p0.x) * (p1.y - p0.y);
    sscore[px] = p2.x;
    int cls = (int)p2.y;
    scls[px] = cls;
    if (p2.x > CONF_TH) atomicAdd(&cnt[cls], 1);
  }
  __syncthreads();

  // ---- phase 2: exclusive prefix sum over 80 class counts (wave-0 shfl scan,
  //      2 classes per lane) ----
  if (t < 64) {
    int c0 = (2 * t < NCLS) ? cnt[2 * t] : 0;
    int c1 = (2 * t + 1 < NCLS) ? cnt[2 * t + 1] : 0;
    int ps = c0 + c1;
    int x = ps;
#pragma unroll
    for (int d = 1; d < 64; d <<= 1) {
      int y = __shfl_up(x, d, 64);
      if (t >= d) x += y;
    }
    int excl = x - ps;   // exclusive scan of pair sums
    if (2 * t < NCLS)     { start[2 * t] = excl;      offs[2 * t] = excl; }
    if (2 * t + 1 < NCLS) { start[2 * t + 1] = excl + c0; offs[2 * t + 1] = excl + c0; }
  }
  __syncthreads();

  // ---- phase 3: scatter valid boxes to class buckets (order irrelevant) ----
#pragma unroll
  for (int k = 0; k < 4; ++k) {
    int px = t + 256 * k;
    if (sscore[px] > CONF_TH) {
      int p = atomicAdd(&offs[scls[px]], 1);
      bucket[p] = px;
    }
  }
  __syncthreads();

  // ---- phase 4: parallel rank within class = exact stable-argsort position
  //      (score desc, original idx asc); ranks are a permutation ----
#pragma unroll
  for (int k = 0; k < 4; ++k) {
    int px = t + 256 * k;
    float s = sscore[px];
    if (s > CONF_TH) {
      int c = scls[px], s0 = start[c], m = cnt[c];
      int r = 0;
      for (int j = 0; j < m; ++j) {
        int jb = bucket[s0 + j];
        float sj = sscore[jb];
        r += (sj > s) || (sj == s && jb < px);
      }
      srank[px] = r;
      sorted[s0 + r] = px;
    }
  }
  __syncthreads();

  // ---- phase 5: parallel suppression bitmasks vs all lower-rank members ----
#pragma unroll
  for (int k = 0; k < 4; ++k) {
    int px = t + 256 * k;
    float s = sscore[px];
    if (s > CONF_TH) {
      int c = scls[px], s0 = start[c];
      int a = srank[px];
      int lim = a < 64 ? a : 64;
      float ax1 = sx1[px], ay1 = sy1[px], ax2 = sx2[px], ay2 = sy2[px];
      float aar = sarea[px];
      unsigned long long mask = 0ull;
      for (int b = 0; b < lim; ++b) {
        int jb = sorted[s0 + b];
        float iw = fminf(ax2, sx2[jb]) - fmaxf(ax1, sx1[jb]);
        float ih = fminf(ay2, sy2[jb]) - fmaxf(ay1, sy1[jb]);
        iw = fmaxf(iw, 0.0f);
        ih = fmaxf(ih, 0.0f);
        float inter = iw * ih;
        float iou = inter / (aar + sarea[jb] - inter + 1e-9f);  // exact ref op order
        if (iou > NMS_TH) mask |= (1ull << b);
      }
      supp[s0 + a] = mask;
    }
  }
  __syncthreads();

  // ---- phase 6: serial greedy scan per class — O(m) register bit-ops ----
  if (t < NCLS) {
    int m = cnt[t], s0 = start[t];
    if (m <= 64) {
      unsigned long long kept = 0ull;
      for (int a = 0; a < m; ++a) {
        unsigned long long sa = supp[s0 + a];   // prefetchable, addr independent
        if ((sa & kept) == 0ull) {
          kept |= (1ull << a);
          keepOut[(size_t)n * HW + sorted[s0 + a]] = 1.0f;
        }
      }
    } else {
      // never expected (Poisson mean ~6 per class); exact O(m^2) fallback
      for (int a = 0; a < m; ++a) {
        int ia = sorted[s0 + a];
        float ax1 = sx1[ia], ay1 = sy1[ia], ax2 = sx2[ia], ay2 = sy2[ia];
        float aar = sarea[ia];
        bool kp = true;
        for (int b = 0; b < a; ++b) {
          if (!bucket[s0 + b]) continue;   // bucket reused as kept-flags
          int jb = sorted[s0 + b];
          float iw = fminf(ax2, sx2[jb]) - fmaxf(ax1, sx1[jb]);
          float ih = fminf(ay2, sy2[jb]) - fmaxf(ay1, sy1[jb]);
          iw = fmaxf(iw, 0.0f);
          ih = fmaxf(ih, 0.0f);
          float inter = iw * ih;
          float iou = inter / (aar + sarea[jb] - inter + 1e-9f);
          if (iou > NMS_TH) { kp = false; break; }
        }
        bucket[s0 + a] = kp ? 1 : 0;
        if (kp) keepOut[(size_t)n * HW + ia] = 1.0f;
      }
    }
  }
}

extern "C" void kernel_launch(void* const* d_in, const int* in_sizes, int n_in,
                              void* d_out, int out_size, void* d_ws, size_t ws_size,
                              hipStream_t stream) {
  const float* preds = (const float*)d_in[0];
  float* out = (float*)d_out;
  float* keepOut = out + (size_t)NIMG * HW * 6;

  decode_kernel<<<(NIMG * HW) / 256, 256, 0, stream>>>(preds, out);
  nms_kernel<<<NIMG, 256, 0, stream>>>(out, keepOut);
}

// Round 4
// 82.072 us; speedup vs baseline: 1.3379x; 1.0108x over previous
//
#include <hip/hip_runtime.h>
#include <math.h>

#define NIMG 64
#define HW   1024
#define NCH  85
#define NCLS 80
#define CONF_TH 0.25f
#define NMS_TH  0.35f

__device__ __forceinline__ float fast_tanh(float x) {
  float e = __expf(2.0f * x);
  return 1.0f - 2.0f * __builtin_amdgcn_rcpf(e + 1.0f);
}
__device__ __forceinline__ float fast_sigmoid(float x) {
  return __builtin_amdgcn_rcpf(1.0f + __expf(-x));
}

// ---------------------------------------------------------------------------
// Fused decode + class-aware NMS. One block per image, 1024 threads = 1 px
// per thread. Decode writes the bbox output fire-and-forget and keeps a SoA
// copy in LDS; NMS (parallel rank + parallel suppression bitmask + O(m)
// serial bit-scan per class) runs entirely from LDS.
// ---------------------------------------------------------------------------
__global__ __launch_bounds__(1024) void fused_kernel(const float* __restrict__ preds,
                                                     float* __restrict__ out,
                                                     float* __restrict__ keepOut) {
  int n = blockIdx.x;
  int t = threadIdx.x;                       // pixel index 0..1023

  __shared__ float sx1[HW], sy1[HW], sx2[HW], sy2[HW], sarea[HW], sscore[HW];
  __shared__ int scls[HW];
  __shared__ int bucket[HW];                 // unordered class members
  __shared__ int sorted[HW];                 // class members, (score desc, idx asc)
  __shared__ int srank[HW];
  __shared__ unsigned long long supp[HW];    // suppression bits vs lower ranks
  __shared__ int cnt[NCLS], offs[NCLS], start[NCLS];

  if (t < NCLS) cnt[t] = 0;

  // ---- decode ----
  const float* base = preds + (size_t)n * (NCH * HW) + t;

  float pobj = base[0];
  float tx = base[1 * HW], ty = base[2 * HW];
  float tw = base[3 * HW], th = base[4 * HW];

  // argmax over 80 classes, 4 chains, exact first-occurrence tie semantics
  float b0 = base[5 * HW], b1 = base[6 * HW], b2 = base[7 * HW], b3 = base[8 * HW];
  int i0 = 0, i1 = 1, i2 = 2, i3 = 3;
#pragma unroll
  for (int c = 4; c < NCLS; c += 4) {
    float v0 = base[(5 + c) * HW];
    float v1 = base[(6 + c) * HW];
    float v2 = base[(7 + c) * HW];
    float v3 = base[(8 + c) * HW];
    if (v0 > b0) { b0 = v0; i0 = c; }
    if (v1 > b1) { b1 = v1; i1 = c + 1; }
    if (v2 > b2) { b2 = v2; i2 = c + 2; }
    if (v3 > b3) { b3 = v3; i3 = c + 3; }
  }
  float best = b0; int bc = i0;
  if (b1 > best || (b1 == best && i1 < bc)) { best = b1; bc = i1; }
  if (b2 > best || (b2 == best && i2 < bc)) { best = b2; bc = i2; }
  if (b3 > best || (b3 == best && i3 < bc)) { best = b3; bc = i3; }

  float score = pobj * best;                 // bit-exact vs reference

  float gx = (float)(t & 31);
  float gy = (float)(t >> 5);
  float bcx = (fast_tanh(tx) + gx) * 0.03125f;
  float bcy = (fast_tanh(ty) + gy) * 0.03125f;
  float bw = fast_sigmoid(tw);
  float bh = fast_sigmoid(th);

  float x1 = bcx - 0.5f * bw, y1 = bcy - 0.5f * bh;
  float x2 = bcx + 0.5f * bw, y2 = bcy + 0.5f * bh;

  size_t gb = (size_t)n * HW + t;
  float2* ob = (float2*)(out + gb * 6);      // fire-and-forget output store
  ob[0] = make_float2(x1, y1);
  ob[1] = make_float2(x2, y2);
  ob[2] = make_float2(score, (float)bc);

  sx1[t] = x1; sy1[t] = y1; sx2[t] = x2; sy2[t] = y2;
  sarea[t] = (x2 - x1) * (y2 - y1);
  sscore[t] = score;
  scls[t] = bc;
  bool valid = score > CONF_TH;
  __syncthreads();

  // ---- count valid per class (cnt zeroed before the barrier) ----
  keepOut[gb] = 0.0f;
  if (valid) atomicAdd(&cnt[bc], 1);
  __syncthreads();

  // ---- exclusive prefix sum over 80 class counts (wave-0 shfl scan) ----
  if (t < 64) {
    int c0 = (2 * t < NCLS) ? cnt[2 * t] : 0;
    int c1 = (2 * t + 1 < NCLS) ? cnt[2 * t + 1] : 0;
    int ps = c0 + c1;
    int x = ps;
#pragma unroll
    for (int d = 1; d < 64; d <<= 1) {
      int y = __shfl_up(x, d, 64);
      if (t >= d) x += y;
    }
    int excl = x - ps;
    if (2 * t < NCLS)     { start[2 * t] = excl;          offs[2 * t] = excl; }
    if (2 * t + 1 < NCLS) { start[2 * t + 1] = excl + c0; offs[2 * t + 1] = excl + c0; }
  }
  __syncthreads();

  // ---- scatter valid boxes to class buckets (order irrelevant) ----
  if (valid) {
    int p = atomicAdd(&offs[bc], 1);
    bucket[p] = t;
  }
  __syncthreads();

  // ---- parallel rank within class = exact stable-argsort position ----
  if (valid) {
    int s0 = start[bc], m = cnt[bc];
    int r = 0;
    for (int j = 0; j < m; ++j) {
      int jb = bucket[s0 + j];
      float sj = sscore[jb];
      r += (sj > score) || (sj == score && jb < t);
    }
    srank[t] = r;
    sorted[s0 + r] = t;
  }
  __syncthreads();

  // ---- parallel suppression bitmasks vs all lower-rank members ----
  if (valid) {
    int s0 = start[bc];
    int a = srank[t];
    int lim = a < 64 ? a : 64;
    unsigned long long mask = 0ull;
    for (int b = 0; b < lim; ++b) {
      int jb = sorted[s0 + b];
      float iw = fminf(x2, sx2[jb]) - fmaxf(x1, sx1[jb]);
      float ih = fminf(y2, sy2[jb]) - fmaxf(y1, sy1[jb]);
      iw = fmaxf(iw, 0.0f);
      ih = fmaxf(ih, 0.0f);
      float inter = iw * ih;
      float aar = (x2 - x1) * (y2 - y1);
      float iou = inter / (aar + sarea[jb] - inter + 1e-9f);  // exact ref op order
      if (iou > NMS_TH) mask |= (1ull << b);
    }
    supp[s0 + a] = mask;
  }
  __syncthreads();

  // ---- serial greedy scan per class: O(m) register bit-ops ----
  if (t < NCLS) {
    int m = cnt[t], s0 = start[t];
    if (m <= 64) {
      unsigned long long kept = 0ull;
      for (int a = 0; a < m; ++a) {
        unsigned long long sa = supp[s0 + a];
        if ((sa & kept) == 0ull) {
          kept |= (1ull << a);
          keepOut[(size_t)n * HW + sorted[s0 + a]] = 1.0f;
        }
      }
    } else {
      // never expected (Poisson mean ~6/class); exact O(m^2) fallback
      for (int a = 0; a < m; ++a) {
        int ia = sorted[s0 + a];
        float ax1 = sx1[ia], ay1 = sy1[ia], ax2 = sx2[ia], ay2 = sy2[ia];
        float aar = sarea[ia];
        bool kp = true;
        for (int b = 0; b < a; ++b) {
          if (!bucket[s0 + b]) continue;     // bucket reused as kept-flags
          int jb = sorted[s0 + b];
          float iw = fminf(ax2, sx2[jb]) - fmaxf(ax1, sx1[jb]);
          float ih = fminf(ay2, sy2[jb]) - fmaxf(ay1, sy1[jb]);
          iw = fmaxf(iw, 0.0f);
          ih = fmaxf(ih, 0.0f);
          float inter = iw * ih;
          float iou = inter / (aar + sarea[jb] - inter + 1e-9f);
          if (iou > NMS_TH) { kp = false; break; }
        }
        bucket[s0 + a] = kp ? 1 : 0;
        if (kp) keepOut[(size_t)n * HW + ia] = 1.0f;
      }
    }
  }
}

extern "C" void kernel_launch(void* const* d_in, const int* in_sizes, int n_in,
                              void* d_out, int out_size, void* d_ws, size_t ws_size,
                              hipStream_t stream) {
  const float* preds = (const float*)d_in[0];
  float* out = (float*)d_out;
  float* keepOut = out + (size_t)NIMG * HW * 6;

  fused_kernel<<<NIMG, HW, 0, stream>>>(preds, out, keepOut);
}

// Round 5
// 73.307 us; speedup vs baseline: 1.4979x; 1.1196x over previous
//
#include <hip/hip_runtime.h>
#include <math.h>

#define NIMG 64
#define HW   1024
#define NCH  85
#define NCLS 80
#define CONF_TH 0.25f
#define NMS_TH  0.35f

__device__ __forceinline__ float fast_tanh(float x) {
  float e = __expf(2.0f * x);
  return 1.0f - 2.0f * __builtin_amdgcn_rcpf(e + 1.0f);
}
__device__ __forceinline__ float fast_sigmoid(float x) {
  return __builtin_amdgcn_rcpf(1.0f + __expf(-x));
}

// Partial argmax over NC class channels starting at absolute channel CL0,
// for 4 consecutive pixels (float4 lanes). Ascending channel order + strict >
// == exact first-occurrence argmax within the quarter.
template <int CL0, int NC>
__device__ __forceinline__ void quarter_argmax(const float* __restrict__ bp,
                                               float4& mv, int4& mi) {
  float4 v = *(const float4*)(bp + (size_t)CL0 * HW);
  float b0 = v.x, b1 = v.y, b2 = v.z, b3 = v.w;
  int i0 = CL0 - 5, i1 = i0, i2 = i0, i3 = i0;
#pragma unroll
  for (int c = 1; c < NC; ++c) {
    float4 u = *(const float4*)(bp + (size_t)(CL0 + c) * HW);
    int ci = CL0 - 5 + c;
    if (u.x > b0) { b0 = u.x; i0 = ci; }
    if (u.y > b1) { b1 = u.y; i1 = ci; }
    if (u.z > b2) { b2 = u.z; i2 = ci; }
    if (u.w > b3) { b3 = u.w; i3 = ci; }
  }
  mv = make_float4(b0, b1, b2, b3);
  mi = make_int4(i0, i1, i2, i3);
}

// ---------------------------------------------------------------------------
// Fused decode + class-aware NMS. One block per image, 1024 threads.
// Decode: float4 loads (1 KB/wave-instr), channel space split across 4
// wave-uniform thread quarters; partials combined per-pixel via LDS.
// NMS: parallel rank + parallel suppression bitmasks + O(m) serial bit-scan.
// ---------------------------------------------------------------------------
__global__ __launch_bounds__(1024) void fused_kernel(const float* __restrict__ preds,
                                                     float* __restrict__ out,
                                                     float* __restrict__ keepOut) {
  int n = blockIdx.x;
  int t = threadIdx.x;
  int q  = t >> 8;          // channel quarter (wave-uniform)
  int pg = t & 255;         // pixel group: pixels 4*pg .. 4*pg+3

  __shared__ float sx1[HW], sy1[HW], sx2[HW], sy2[HW], sarea[HW], sscore[HW];
  __shared__ int scls[HW];
  __shared__ int bucket[HW];                 // unordered class members
  __shared__ int sorted[HW];                 // (score desc, idx asc) order
  __shared__ int srank[HW];
  __shared__ unsigned long long supp[HW];    // suppression bits vs lower ranks
  __shared__ int cnt[NCLS], offs[NCLS], start[NCLS];
  __shared__ float pmaxv[4][HW];             // per-quarter partial max  [q][pixel]
  __shared__ int   pmaxi[4][HW];             // per-quarter partial argmax
  __shared__ float sobj[HW];
  __shared__ float sreg[4][HW];              // tx, ty, tw, th

  if (t < NCLS) cnt[t] = 0;

  // ---- decode phase A: cooperative float4 channel loads ----
  const float* bp = preds + (size_t)n * (NCH * HW) + 4 * pg;
  float4 mv; int4 mi;
  if (q == 0) {
    float4 vobj = *(const float4*)(bp);
    ((float4*)sobj)[pg] = vobj;
#pragma unroll
    for (int r = 0; r < 4; ++r) {
      float4 vr = *(const float4*)(bp + (size_t)(1 + r) * HW);
      ((float4*)&sreg[r][0])[pg] = vr;
    }
    quarter_argmax<5, 16>(bp, mv, mi);     // classes  0..15
  } else if (q == 1) {
    quarter_argmax<21, 21>(bp, mv, mi);    // classes 16..36
  } else if (q == 2) {
    quarter_argmax<42, 21>(bp, mv, mi);    // classes 37..57
  } else {
    quarter_argmax<63, 22>(bp, mv, mi);    // classes 58..79
  }
  ((float4*)&pmaxv[q][0])[pg] = mv;
  ((int4*)&pmaxi[q][0])[pg] = mi;
  __syncthreads();

  // ---- decode phase B: per-pixel combine (ascending q, strict > ==
  //      exact first-occurrence across quarters) + box math ----
  float pobj = sobj[t];
  float tx = sreg[0][t], ty = sreg[1][t], tw = sreg[2][t], th = sreg[3][t];
  float best = pmaxv[0][t]; int bc = pmaxi[0][t];
#pragma unroll
  for (int qq = 1; qq < 4; ++qq) {
    float v = pmaxv[qq][t];
    if (v > best) { best = v; bc = pmaxi[qq][t]; }
  }
  float score = pobj * best;               // bit-exact vs reference

  float gx = (float)(t & 31);
  float gy = (float)(t >> 5);
  float bcx = (fast_tanh(tx) + gx) * 0.03125f;
  float bcy = (fast_tanh(ty) + gy) * 0.03125f;
  float bw = fast_sigmoid(tw);
  float bh = fast_sigmoid(th);

  float x1 = bcx - 0.5f * bw, y1 = bcy - 0.5f * bh;
  float x2 = bcx + 0.5f * bw, y2 = bcy + 0.5f * bh;

  size_t gb = (size_t)n * HW + t;
  float2* ob = (float2*)(out + gb * 6);    // fire-and-forget output store
  ob[0] = make_float2(x1, y1);
  ob[1] = make_float2(x2, y2);
  ob[2] = make_float2(score, (float)bc);

  sx1[t] = x1; sy1[t] = y1; sx2[t] = x2; sy2[t] = y2;
  float aar = (x2 - x1) * (y2 - y1);
  sarea[t] = aar;
  sscore[t] = score;
  scls[t] = bc;
  bool valid = score > CONF_TH;
  keepOut[gb] = 0.0f;
  __syncthreads();

  // ---- count valid per class ----
  if (valid) atomicAdd(&cnt[bc], 1);
  __syncthreads();

  // ---- exclusive prefix sum over 80 class counts (wave-0 shfl scan) ----
  if (t < 64) {
    int c0 = (2 * t < NCLS) ? cnt[2 * t] : 0;
    int c1 = (2 * t + 1 < NCLS) ? cnt[2 * t + 1] : 0;
    int ps = c0 + c1;
    int x = ps;
#pragma unroll
    for (int d = 1; d < 64; d <<= 1) {
      int y = __shfl_up(x, d, 64);
      if (t >= d) x += y;
    }
    int excl = x - ps;
    if (2 * t < NCLS)     { start[2 * t] = excl;          offs[2 * t] = excl; }
    if (2 * t + 1 < NCLS) { start[2 * t + 1] = excl + c0; offs[2 * t + 1] = excl + c0; }
  }
  __syncthreads();

  // ---- scatter valid boxes to class buckets (order irrelevant) ----
  if (valid) {
    int p = atomicAdd(&offs[bc], 1);
    bucket[p] = t;
  }
  __syncthreads();

  // ---- parallel rank within class = exact stable-argsort position ----
  if (valid) {
    int s0 = start[bc], m = cnt[bc];
    int r = 0;
    for (int j = 0; j < m; ++j) {
      int jb = bucket[s0 + j];
      float sj = sscore[jb];
      r += (sj > score) || (sj == score && jb < t);
    }
    srank[t] = r;
    sorted[s0 + r] = t;
  }
  __syncthreads();

  // ---- parallel suppression bitmasks vs all lower-rank members ----
  if (valid) {
    int s0 = start[bc];
    int a = srank[t];
    int lim = a < 64 ? a : 64;
    unsigned long long mask = 0ull;
    for (int b = 0; b < lim; ++b) {
      int jb = sorted[s0 + b];
      float iw = fminf(x2, sx2[jb]) - fmaxf(x1, sx1[jb]);
      float ih = fminf(y2, sy2[jb]) - fmaxf(y1, sy1[jb]);
      iw = fmaxf(iw, 0.0f);
      ih = fmaxf(ih, 0.0f);
      float inter = iw * ih;
      float iou = inter / (aar + sarea[jb] - inter + 1e-9f);  // exact ref op order
      if (iou > NMS_TH) mask |= (1ull << b);
    }
    supp[s0 + a] = mask;
  }
  __syncthreads();

  // ---- serial greedy scan per class: O(m) register bit-ops ----
  if (t < NCLS) {
    int m = cnt[t], s0 = start[t];
    if (m <= 64) {
      unsigned long long kept = 0ull;
      for (int a = 0; a < m; ++a) {
        unsigned long long sa = supp[s0 + a];
        if ((sa & kept) == 0ull) {
          kept |= (1ull << a);
          keepOut[(size_t)n * HW + sorted[s0 + a]] = 1.0f;
        }
      }
    } else {
      // never expected (Poisson mean ~6/class); exact O(m^2) fallback
      for (int a = 0; a < m; ++a) {
        int ia = sorted[s0 + a];
        float ax1 = sx1[ia], ay1 = sy1[ia], ax2 = sx2[ia], ay2 = sy2[ia];
        float ar2 = sarea[ia];
        bool kp = true;
        for (int b = 0; b < a; ++b) {
          if (!bucket[s0 + b]) continue;   // bucket reused as kept-flags
          int jb = sorted[s0 + b];
          float iw = fminf(ax2, sx2[jb]) - fmaxf(ax1, sx1[jb]);
          float ih = fminf(ay2, sy2[jb]) - fmaxf(ay1, sy1[jb]);
          iw = fmaxf(iw, 0.0f);
          ih = fmaxf(ih, 0.0f);
          float inter = iw * ih;
          float iou = inter / (ar2 + sarea[jb] - inter + 1e-9f);
          if (iou > NMS_TH) { kp = false; break; }
        }
        bucket[s0 + a] = kp ? 1 : 0;
        if (kp) keepOut[(size_t)n * HW + ia] = 1.0f;
      }
    }
  }
}

extern "C" void kernel_launch(void* const* d_in, const int* in_sizes, int n_in,
                              void* d_out, int out_size, void* d_ws, size_t ws_size,
                              hipStream_t stream) {
  const float* preds = (const float*)d_in[0];
  float* out = (float*)d_out;
  float* keepOut = out + (size_t)NIMG * HW * 6;

  fused_kernel<<<NIMG, HW, 0, stream>>>(preds, out, keepOut);
}